// Round 14
// baseline (914.538 us; speedup 1.0000x reference)
//
#include <hip/hip_runtime.h>

#define BB 256
#define TT 2048
#define NN 64

// ---------- validated cross-lane helpers ----------
template <int K>
__device__ __forceinline__ int rot_i(int v) {  // row_ror:K within 16-lane rows
  return __builtin_amdgcn_update_dpp(0, v, 0x120 | K, 0xF, 0xF, true);
}
template <int K>
__device__ __forceinline__ float rot_f(float v) {
  return __int_as_float(rot_i<K>(__float_as_int(v)));
}
// Selection-free pair combines (correct under ANY pair-exchange semantics).
__device__ __forceinline__ float pair16_max(float m) {
  int a = __float_as_int(m), b = a;
  asm volatile("v_permlane16_swap_b32 %0, %1" : "+v"(a), "+v"(b));
  return fmaxf(__int_as_float(a), __int_as_float(b));
}
__device__ __forceinline__ float pair32_max(float m) {
  int a = __float_as_int(m), b = a;
  asm volatile("v_permlane32_swap_b32 %0, %1" : "+v"(a), "+v"(b));
  return fmaxf(__int_as_float(a), __int_as_float(b));
}
__device__ __forceinline__ int pair16_min(int v) {
  int a = v, b = v;
  asm volatile("v_permlane16_swap_b32 %0, %1" : "+v"(a), "+v"(b));
  return a < b ? a : b;
}
__device__ __forceinline__ int pair32_min(int v) {
  int a = v, b = v;
  asm volatile("v_permlane32_swap_b32 %0, %1" : "+v"(a), "+v"(b));
  return a < b ? a : b;
}
// full-wave max in every lane: rotate-reduce within rows + pair combines
__device__ __forceinline__ float wave_max64(float v) {
  float m = v;
  m = fmaxf(m, rot_f<8>(m));
  m = fmaxf(m, rot_f<4>(m));
  m = fmaxf(m, rot_f<2>(m));
  m = fmaxf(m, rot_f<1>(m));
  m = pair16_max(m);
  m = pair32_max(m);
  return m;
}

// ===================== FAST PATH =====================
// Single wave per batch; alpha register-resident. Cross-row exchange via
// ping-pong LDS (write iter t, read iter t+1) + a per-iteration compiler
// memory fence: reorder-proof (R13 bug: provably-distinct LDS addresses let
// hipcc hoist reads above the same-iteration write -> stale/uninit data).
__global__ __launch_bounds__(64, 1)
void crf_viterbi_fast(const float* __restrict__ x,
                      const int* __restrict__ seq_len,
                      const float* __restrict__ trans,
                      float* __restrict__ out,
                      float* __restrict__ hist) {
  const int b = blockIdx.x;
  const int lane = threadIdx.x;

  __shared__ float alp[2][NN];       // alpha exchange, ping-pong by t&1
  __shared__ float transT[NN * 65];  // transT[j][i] = trans[i][j], pad 65

  const float* xb = x + (size_t)b * TT * NN;
  float* hb = hist + (size_t)b * TT * NN;
  const int slen = seq_len[b];
  const int bTT = b * TT;

  for (int r = 0; r < NN; ++r) transT[lane * 65 + r] = trans[r * NN + lane];

  // tcg[k][lane] = trans[ sigma_k(lane) ^ g*16 ][ lane ], sigma_k = the SAME
  // DPP rotation applied to the lane-id register (direction-proof pairing).
  float tc0[16], tc1[16], tc2[16], tc3[16];
  {
    int s = lane;
    tc0[0] = trans[s * NN + lane];
    tc1[0] = trans[(s ^ 16) * NN + lane];
    tc2[0] = trans[(s ^ 32) * NN + lane];
    tc3[0] = trans[(s ^ 48) * NN + lane];
  }
#define TCL(K) { int s = rot_i<K>(lane);            \
    tc0[K] = trans[s * NN + lane];                   \
    tc1[K] = trans[(s ^ 16) * NN + lane];            \
    tc2[K] = trans[(s ^ 32) * NN + lane];            \
    tc3[K] = trans[(s ^ 48) * NN + lane]; }
  TCL(1) TCL(2) TCL(3) TCL(4) TCL(5) TCL(6) TCL(7) TCL(8)
  TCL(9) TCL(10) TCL(11) TCL(12) TCL(13) TCL(14) TCL(15)
#undef TCL

  // ---------------- forward (value-only, barrier-free) ----------------
  float av = xb[lane];
  hb[lane] = av;       // history row 0
  alp[0][lane] = av;   // exchange buffer parity 0 holds alpha_0
  float xn1 = xb[NN + lane];
  float xn2 = xb[2 * NN + lane];
  float xn3 = xb[3 * NN + lane];

  for (int t = 1; t < slen; ++t) {
    // Compiler fence: previous iteration's alp store must precede this
    // iteration's partner reads (hipcc can otherwise prove lane^16 != lane
    // and reorder). Zero runtime cost; same-wave DS pipe is in-order.
    asm volatile("" ::: "memory");

    const int pr = (t + 1) & 1;  // parity holding alpha_{t-1}
    float w1 = alp[pr][lane ^ 16];
    float w2 = alp[pr][lane ^ 32];
    float w3 = alp[pr][lane ^ 48];

    float xv = xn1; xn1 = xn2; xn2 = xn3;
    {
      int tn = (t + 3 < TT) ? (t + 3) : (TT - 1);  // consumed at iter t+3
      xn3 = xb[(size_t)tn * NN + lane];
    }

    // cand(g,k) = alpha[sigma_k(l)^g16] + trans[sigma_k(l)^g16][l]
#define Q(K) fmaxf(fmaxf(rot_f<K>(av) + tc0[K], rot_f<K>(w1) + tc1[K]), \
                   fmaxf(rot_f<K>(w2) + tc2[K], rot_f<K>(w3) + tc3[K]))
    float m0 = fmaxf(fmaxf(av + tc0[0], w1 + tc1[0]),
                     fmaxf(w2 + tc2[0], w3 + tc3[0]));
    float m1 = Q(1), m2 = Q(2), m3 = Q(3);
    m0 = fmaxf(m0, Q(4));  m1 = fmaxf(m1, Q(5));
    m2 = fmaxf(m2, Q(6));  m3 = fmaxf(m3, Q(7));
    m0 = fmaxf(m0, Q(8));  m1 = fmaxf(m1, Q(9));
    m2 = fmaxf(m2, Q(10)); m3 = fmaxf(m3, Q(11));
    m0 = fmaxf(m0, Q(12)); m1 = fmaxf(m1, Q(13));
    m2 = fmaxf(m2, Q(14)); m3 = fmaxf(m3, Q(15));
#undef Q
    float m = fmaxf(fmaxf(m0, m1), fmaxf(m2, m3));
    av = m + xv;

    alp[t & 1][lane] = av;           // for iteration t+1's partner reads
    hb[(size_t)t * NN + lane] = av;  // fire-and-forget history store
  }

  // ------------- final score/argmax (selection-free, exact) -------------
  const float best = wave_max64(av);
  const int last = ((int)__builtin_ctzll(__ballot(av == best))) & 63;

  // tags[t] = last for t >= slen-1 (identity region)
  for (int t = slen - 1 + lane; t < TT; t += NN) out[bTT + t] = (float)last;
  if (lane == 0) out[BB * TT + b] = best;  // exact fp32 score

  // ------------- traceback: recompute bp from alpha history -------------
  int start = slen - 2;
  if (start >= 0) {
    asm volatile("s_waitcnt vmcnt(0)" ::: "memory");  // history visible
    int tag = last;
#define LDR(ROW) hb[(size_t)(((ROW) > 0) ? (ROW) : 0) * NN + lane]
    float r0 = LDR(start), r1 = LDR(start - 1), r2 = LDR(start - 2),
          r3 = LDR(start - 3);
    int t = start;
#define TSTEP(RREG, TIDX) {                                            \
      float val = (RREG) + transT[tag * 65 + lane];                    \
      float mm = wave_max64(val);                                      \
      tag = ((int)__builtin_ctzll(__ballot(val == mm))) & 63;          \
      if (lane == 0) out[bTT + (TIDX)] = (float)tag;                   \
    }
    while (t >= 3) {
      TSTEP(r0, t);     r0 = LDR(t - 4);
      TSTEP(r1, t - 1); r1 = LDR(t - 5);
      TSTEP(r2, t - 2); r2 = LDR(t - 6);
      TSTEP(r3, t - 3); r3 = LDR(t - 7);
      t -= 4;
    }
    if (t >= 0) TSTEP(r0, t);
    if (t >= 1) TSTEP(r1, t - 1);
    if (t >= 2) TSTEP(r2, t - 2);
#undef TSTEP
#undef LDR
  }
}

// ===================== FALLBACK (R10, known-passing) =====================
__global__ __launch_bounds__(256, 1)
void crf_viterbi_fb(const float* __restrict__ x,
                    const int* __restrict__ seq_len,
                    const float* __restrict__ trans,
                    float* __restrict__ out) {
  const int b = blockIdx.x;
  const int tid = threadIdx.x;
  const int lane = tid & 63;
  const int w = tid >> 6;
  const int c = lane & 15;
  const int jc = (w << 4) + c;

  __shared__ __align__(16) float alpha_s[2][NN];
  __shared__ unsigned char bp_s[(TT - 1) * NN];
  __shared__ int map_s[4][NN];

  const float* xb = x + (size_t)b * TT * NN;
  const int slen = seq_len[b];

  int idxv[16];
  idxv[0] = lane;
  idxv[1] = rot_i<1>(lane);   idxv[2] = rot_i<2>(lane);
  idxv[3] = rot_i<3>(lane);   idxv[4] = rot_i<4>(lane);
  idxv[5] = rot_i<5>(lane);   idxv[6] = rot_i<6>(lane);
  idxv[7] = rot_i<7>(lane);   idxv[8] = rot_i<8>(lane);
  idxv[9] = rot_i<9>(lane);   idxv[10] = rot_i<10>(lane);
  idxv[11] = rot_i<11>(lane); idxv[12] = rot_i<12>(lane);
  idxv[13] = rot_i<13>(lane); idxv[14] = rot_i<14>(lane);
  idxv[15] = rot_i<15>(lane);

  float tcv[16];
#pragma unroll
  for (int k = 0; k < 16; ++k) tcv[k] = trans[idxv[k] * NN + jc];

  if (w == 0) alpha_s[0][lane] = xb[lane];
  __syncthreads();

  float xn1 = xb[NN + jc];
  float xn2 = xb[2 * NN + jc];

  for (int t = 1; t < slen; ++t) {
    float xv = xn1;
    xn1 = xn2;
    {
      int tn = (t + 2 < TT) ? (t + 2) : (TT - 1);
      xn2 = xb[(size_t)tn * NN + jc];
    }
    const int pr = (t + 1) & 1;
    const int pw = t & 1;

    float avf = alpha_s[pr][lane];

    float c0 = avf + tcv[0];
    float c1 = rot_f<1>(avf) + tcv[1];
    float c2 = rot_f<2>(avf) + tcv[2];
    float c3 = rot_f<3>(avf) + tcv[3];
    float c4 = rot_f<4>(avf) + tcv[4];
    float c5 = rot_f<5>(avf) + tcv[5];
    float c6 = rot_f<6>(avf) + tcv[6];
    float c7 = rot_f<7>(avf) + tcv[7];
    float c8 = rot_f<8>(avf) + tcv[8];
    float c9 = rot_f<9>(avf) + tcv[9];
    float c10 = rot_f<10>(avf) + tcv[10];
    float c11 = rot_f<11>(avf) + tcv[11];
    float c12 = rot_f<12>(avf) + tcv[12];
    float c13 = rot_f<13>(avf) + tcv[13];
    float c14 = rot_f<14>(avf) + tcv[14];
    float c15 = rot_f<15>(avf) + tcv[15];

    float m = fmaxf(fmaxf(fmaxf(fmaxf(c0, c1), fmaxf(c2, c3)),
                          fmaxf(fmaxf(c4, c5), fmaxf(c6, c7))),
                    fmaxf(fmaxf(fmaxf(c8, c9), fmaxf(c10, c11)),
                          fmaxf(fmaxf(c12, c13), fmaxf(c14, c15))));
    m = pair16_max(m);
    m = pair32_max(m);

    int s0 = (c0 == m) ? idxv[0] : NN;
    int s1 = (c1 == m) ? idxv[1] : NN;
    int s2 = (c2 == m) ? idxv[2] : NN;
    int s3 = (c3 == m) ? idxv[3] : NN;
    int s4 = (c4 == m) ? idxv[4] : NN;
    int s5 = (c5 == m) ? idxv[5] : NN;
    int s6 = (c6 == m) ? idxv[6] : NN;
    int s7 = (c7 == m) ? idxv[7] : NN;
    int s8 = (c8 == m) ? idxv[8] : NN;
    int s9 = (c9 == m) ? idxv[9] : NN;
    int s10 = (c10 == m) ? idxv[10] : NN;
    int s11 = (c11 == m) ? idxv[11] : NN;
    int s12 = (c12 == m) ? idxv[12] : NN;
    int s13 = (c13 == m) ? idxv[13] : NN;
    int s14 = (c14 == m) ? idxv[14] : NN;
    int s15 = (c15 == m) ? idxv[15] : NN;
    int idx = min(min(min(min(s0, s1), min(s2, s3)),
                      min(min(s4, s5), min(s6, s7))),
                  min(min(min(s8, s9), min(s10, s11)),
                      min(min(s12, s13), min(s14, s15))));
    idx = pair16_min(idx);
    idx = pair32_min(idx);

    if (lane < 16) {
      alpha_s[pw][jc] = m + xv;
      bp_s[(t - 1) * NN + jc] = (unsigned char)idx;
    }
    asm volatile("s_waitcnt lgkmcnt(0)\n\ts_barrier" ::: "memory");
  }

  const int pf = (slen - 1) & 1;
  float best = alpha_s[pf][lane];
  int last = lane;
#pragma unroll
  for (int mask = 1; mask < 64; mask <<= 1) {
    float ov = __shfl_xor(best, mask, 64);
    int oi = __shfl_xor(last, mask, 64);
    bool take = (ov > best) || (ov == best && oi < last);
    best = take ? ov : best;
    last = take ? oi : last;
  }
  const float lastf = (float)last;
  const int bTT = b * TT;

  for (int t = slen - 1 + tid; t < TT; t += 256) out[bTT + t] = lastf;
  if (tid == 0) out[BB * TT + b] = best;

  const int lo = 512 * w;
  const int hi = ((512 * (w + 1) - 1) < (slen - 2)) ? (512 * (w + 1) - 1)
                                                    : (slen - 2);
  if (w > 0) {
    int s = lane;
    for (int r = hi; r >= lo; --r) s = bp_s[r * NN + s];
    map_s[w][lane] = s;
  }
  __syncthreads();

  const int e3 = last;
  const int e2 = map_s[3][e3];
  const int e1 = map_s[2][e2];
  const int e0 = map_s[1][e1];
  const int entry = (w == 3) ? e3 : (w == 2) ? e2 : (w == 1) ? e1 : e0;

  if (lane == 0) {
    int s = entry;
    for (int r = hi; r >= lo; --r) {
      s = bp_s[r * NN + s];
      out[bTT + r] = (float)s;
    }
  }
}

extern "C" void kernel_launch(void* const* d_in, const int* in_sizes, int n_in,
                              void* d_out, int out_size, void* d_ws, size_t ws_size,
                              hipStream_t stream) {
  const float* x = (const float*)d_in[0];
  const int* seq_len = (const int*)d_in[1];
  const float* trans = (const float*)d_in[2];
  float* out = (float*)d_out;

  const size_t need = (size_t)BB * TT * NN * sizeof(float);  // 128 MiB history
  if (ws_size >= need) {
    crf_viterbi_fast<<<BB, 64, 0, stream>>>(x, seq_len, trans, out,
                                            (float*)d_ws);
  } else {
    crf_viterbi_fb<<<BB, 256, 0, stream>>>(x, seq_len, trans, out);
  }
}

// Round 16
// 887.269 us; speedup vs baseline: 1.0307x; 1.0307x over previous
//
#include <hip/hip_runtime.h>

#define BB 256
#define TT 2048
#define NN 64

// ---------- validated cross-lane helpers ----------
template <int K>
__device__ __forceinline__ int rot_i(int v) {  // row_ror:K within 16-lane rows
  return __builtin_amdgcn_update_dpp(0, v, 0x120 | K, 0xF, 0xF, true);
}
template <int K>
__device__ __forceinline__ float rot_f(float v) {
  return __int_as_float(rot_i<K>(__float_as_int(v)));
}
__device__ __forceinline__ void pswap16(int &a, int &b) {
  asm volatile("v_permlane16_swap_b32 %0, %1" : "+v"(a), "+v"(b));
}
__device__ __forceinline__ void pswap32(int &a, int &b) {
  asm volatile("v_permlane32_swap_b32 %0, %1" : "+v"(a), "+v"(b));
}
// Selection-free pair combines (R10/R14-validated; correct under any
// pair-exchange semantics since both outputs are consumed symmetrically).
__device__ __forceinline__ float pair16_max(float m) {
  int a = __float_as_int(m), b = a;
  pswap16(a, b);
  return fmaxf(__int_as_float(a), __int_as_float(b));
}
__device__ __forceinline__ float pair32_max(float m) {
  int a = __float_as_int(m), b = a;
  pswap32(a, b);
  return fmaxf(__int_as_float(a), __int_as_float(b));
}
__device__ __forceinline__ int pair16_min(int v) {
  int a = v, b = v;
  pswap16(a, b);
  return a < b ? a : b;
}
__device__ __forceinline__ int pair32_min(int v) {
  int a = v, b = v;
  pswap32(a, b);
  return a < b ? a : b;
}
// full-wave max in every lane
__device__ __forceinline__ float wave_max64(float v) {
  float m = v;
  m = fmaxf(m, rot_f<8>(m));
  m = fmaxf(m, rot_f<4>(m));
  m = fmaxf(m, rot_f<2>(m));
  m = fmaxf(m, rot_f<1>(m));
  m = pair16_max(m);
  m = pair32_max(m);
  return m;
}

// ===================== FAST PATH =====================
// Single wave per batch; alpha register-resident. Cross-row exchange via
// __shfl_xor (ds_bpermute: documented per-lane pull, validated in R8 with
// absmax 0.0). NO selected-permlane (failed 3x: R12/R15), NO LDS aliasing,
// NO fences -> compiler schedules/pipelines the register loop freely.
__global__ __launch_bounds__(64, 1)
void crf_viterbi_fast(const float* __restrict__ x,
                      const int* __restrict__ seq_len,
                      const float* __restrict__ trans,
                      float* __restrict__ out,
                      float* __restrict__ hist) {
  const int b = blockIdx.x;
  const int lane = threadIdx.x;

  __shared__ float transT[NN * 65];  // transT[j][i] = trans[i][j], pad 65

  const float* xb = x + (size_t)b * TT * NN;
  float* hb = hist + (size_t)b * TT * NN;
  const int slen = seq_len[b];
  const int bTT = b * TT;

  for (int r = 0; r < NN; ++r) transT[lane * 65 + r] = trans[r * NN + lane];

  // tcg[k][lane] = trans[ sigma_k(lane) ^ g*16 ][ lane ] (XOR row-pairing,
  // arithmetic -- R14-validated fill; sigma_k = same DPP applied to lane-id).
  float tc0[16], tc1[16], tc2[16], tc3[16];
  {
    int s = lane;
    tc0[0] = trans[s * NN + lane];
    tc1[0] = trans[(s ^ 16) * NN + lane];
    tc2[0] = trans[(s ^ 32) * NN + lane];
    tc3[0] = trans[(s ^ 48) * NN + lane];
  }
#define TCL(K) { int s = rot_i<K>(lane);            \
    tc0[K] = trans[s * NN + lane];                   \
    tc1[K] = trans[(s ^ 16) * NN + lane];            \
    tc2[K] = trans[(s ^ 32) * NN + lane];            \
    tc3[K] = trans[(s ^ 48) * NN + lane]; }
  TCL(1) TCL(2) TCL(3) TCL(4) TCL(5) TCL(6) TCL(7) TCL(8)
  TCL(9) TCL(10) TCL(11) TCL(12) TCL(13) TCL(14) TCL(15)
#undef TCL

  // ---------------- forward (value-only, register loop) ----------------
  float av = xb[lane];
  hb[lane] = av;  // history row 0
  float xn1 = xb[NN + lane];
  float xn2 = xb[2 * NN + lane];
  float xn3 = xb[3 * NN + lane];

  for (int t = 1; t < slen; ++t) {
    float xv = xn1; xn1 = xn2; xn2 = xn3;
    {
      int tn = (t + 3 < TT) ? (t + 3) : (TT - 1);  // consumed at iter t+3
      xn3 = xb[(size_t)tn * NN + lane];
    }

    // partner-row alphas: documented ds_bpermute pulls (issue first; the
    // own-row candidate group below overlaps their ~60cy latency)
    float w1 = __shfl_xor(av, 16, 64);  // av[lane^16]
    float w2 = __shfl_xor(av, 32, 64);  // av[lane^32]
    float w3 = __shfl_xor(av, 48, 64);  // av[lane^48]

    // cand(g,k) = alpha[sigma_k(l)^g16] + trans[sigma_k(l)^g16][l]
#define Q(K) fmaxf(fmaxf(rot_f<K>(av) + tc0[K], rot_f<K>(w1) + tc1[K]), \
                   fmaxf(rot_f<K>(w2) + tc2[K], rot_f<K>(w3) + tc3[K]))
    float m0 = fmaxf(fmaxf(av + tc0[0], w1 + tc1[0]),
                     fmaxf(w2 + tc2[0], w3 + tc3[0]));
    float m1 = Q(1), m2 = Q(2), m3 = Q(3);
    m0 = fmaxf(m0, Q(4));  m1 = fmaxf(m1, Q(5));
    m2 = fmaxf(m2, Q(6));  m3 = fmaxf(m3, Q(7));
    m0 = fmaxf(m0, Q(8));  m1 = fmaxf(m1, Q(9));
    m2 = fmaxf(m2, Q(10)); m3 = fmaxf(m3, Q(11));
    m0 = fmaxf(m0, Q(12)); m1 = fmaxf(m1, Q(13));
    m2 = fmaxf(m2, Q(14)); m3 = fmaxf(m3, Q(15));
#undef Q
    float m = fmaxf(fmaxf(m0, m1), fmaxf(m2, m3));
    av = m + xv;

    hb[(size_t)t * NN + lane] = av;  // fire-and-forget history store
  }

  // ------------- final score/argmax (selection-free, exact) -------------
  const float best = wave_max64(av);
  const int last = ((int)__builtin_ctzll(__ballot(av == best))) & 63;

  // tags[t] = last for t >= slen-1 (identity region)
  for (int t = slen - 1 + lane; t < TT; t += NN) out[bTT + t] = (float)last;
  if (lane == 0) out[BB * TT + b] = best;  // exact fp32 score

  // ------------- traceback: recompute bp from alpha history -------------
  int start = slen - 2;
  if (start >= 0) {
    asm volatile("s_waitcnt vmcnt(0)" ::: "memory");  // history visible
    int tag = last;
#define LDR(ROW) hb[(size_t)(((ROW) > 0) ? (ROW) : 0) * NN + lane]
    float r0 = LDR(start), r1 = LDR(start - 1), r2 = LDR(start - 2),
          r3 = LDR(start - 3);
    int t = start;
#define TSTEP(RREG, TIDX) {                                            \
      float val = (RREG) + transT[tag * 65 + lane];                    \
      float mm = wave_max64(val);                                      \
      tag = ((int)__builtin_ctzll(__ballot(val == mm))) & 63;          \
      if (lane == 0) out[bTT + (TIDX)] = (float)tag;                   \
    }
    while (t >= 3) {
      TSTEP(r0, t);     r0 = LDR(t - 4);
      TSTEP(r1, t - 1); r1 = LDR(t - 5);
      TSTEP(r2, t - 2); r2 = LDR(t - 6);
      TSTEP(r3, t - 3); r3 = LDR(t - 7);
      t -= 4;
    }
    if (t >= 0) TSTEP(r0, t);
    if (t >= 1) TSTEP(r1, t - 1);
    if (t >= 2) TSTEP(r2, t - 2);
#undef TSTEP
#undef LDR
  }
}

// ===================== FALLBACK (R10, known-passing) =====================
__global__ __launch_bounds__(256, 1)
void crf_viterbi_fb(const float* __restrict__ x,
                    const int* __restrict__ seq_len,
                    const float* __restrict__ trans,
                    float* __restrict__ out) {
  const int b = blockIdx.x;
  const int tid = threadIdx.x;
  const int lane = tid & 63;
  const int w = tid >> 6;
  const int c = lane & 15;
  const int jc = (w << 4) + c;

  __shared__ __align__(16) float alpha_s[2][NN];
  __shared__ unsigned char bp_s[(TT - 1) * NN];
  __shared__ int map_s[4][NN];

  const float* xb = x + (size_t)b * TT * NN;
  const int slen = seq_len[b];

  int idxv[16];
  idxv[0] = lane;
  idxv[1] = rot_i<1>(lane);   idxv[2] = rot_i<2>(lane);
  idxv[3] = rot_i<3>(lane);   idxv[4] = rot_i<4>(lane);
  idxv[5] = rot_i<5>(lane);   idxv[6] = rot_i<6>(lane);
  idxv[7] = rot_i<7>(lane);   idxv[8] = rot_i<8>(lane);
  idxv[9] = rot_i<9>(lane);   idxv[10] = rot_i<10>(lane);
  idxv[11] = rot_i<11>(lane); idxv[12] = rot_i<12>(lane);
  idxv[13] = rot_i<13>(lane); idxv[14] = rot_i<14>(lane);
  idxv[15] = rot_i<15>(lane);

  float tcv[16];
#pragma unroll
  for (int k = 0; k < 16; ++k) tcv[k] = trans[idxv[k] * NN + jc];

  if (w == 0) alpha_s[0][lane] = xb[lane];
  __syncthreads();

  float xn1 = xb[NN + jc];
  float xn2 = xb[2 * NN + jc];

  for (int t = 1; t < slen; ++t) {
    float xv = xn1;
    xn1 = xn2;
    {
      int tn = (t + 2 < TT) ? (t + 2) : (TT - 1);
      xn2 = xb[(size_t)tn * NN + jc];
    }
    const int pr = (t + 1) & 1;
    const int pw = t & 1;

    float avf = alpha_s[pr][lane];

    float c0 = avf + tcv[0];
    float c1 = rot_f<1>(avf) + tcv[1];
    float c2 = rot_f<2>(avf) + tcv[2];
    float c3 = rot_f<3>(avf) + tcv[3];
    float c4 = rot_f<4>(avf) + tcv[4];
    float c5 = rot_f<5>(avf) + tcv[5];
    float c6 = rot_f<6>(avf) + tcv[6];
    float c7 = rot_f<7>(avf) + tcv[7];
    float c8 = rot_f<8>(avf) + tcv[8];
    float c9 = rot_f<9>(avf) + tcv[9];
    float c10 = rot_f<10>(avf) + tcv[10];
    float c11 = rot_f<11>(avf) + tcv[11];
    float c12 = rot_f<12>(avf) + tcv[12];
    float c13 = rot_f<13>(avf) + tcv[13];
    float c14 = rot_f<14>(avf) + tcv[14];
    float c15 = rot_f<15>(avf) + tcv[15];

    float m = fmaxf(fmaxf(fmaxf(fmaxf(c0, c1), fmaxf(c2, c3)),
                          fmaxf(fmaxf(c4, c5), fmaxf(c6, c7))),
                    fmaxf(fmaxf(fmaxf(c8, c9), fmaxf(c10, c11)),
                          fmaxf(fmaxf(c12, c13), fmaxf(c14, c15))));
    m = pair16_max(m);
    m = pair32_max(m);

    int s0 = (c0 == m) ? idxv[0] : NN;
    int s1 = (c1 == m) ? idxv[1] : NN;
    int s2 = (c2 == m) ? idxv[2] : NN;
    int s3 = (c3 == m) ? idxv[3] : NN;
    int s4 = (c4 == m) ? idxv[4] : NN;
    int s5 = (c5 == m) ? idxv[5] : NN;
    int s6 = (c6 == m) ? idxv[6] : NN;
    int s7 = (c7 == m) ? idxv[7] : NN;
    int s8 = (c8 == m) ? idxv[8] : NN;
    int s9 = (c9 == m) ? idxv[9] : NN;
    int s10 = (c10 == m) ? idxv[10] : NN;
    int s11 = (c11 == m) ? idxv[11] : NN;
    int s12 = (c12 == m) ? idxv[12] : NN;
    int s13 = (c13 == m) ? idxv[13] : NN;
    int s14 = (c14 == m) ? idxv[14] : NN;
    int s15 = (c15 == m) ? idxv[15] : NN;
    int idx = min(min(min(min(s0, s1), min(s2, s3)),
                      min(min(s4, s5), min(s6, s7))),
                  min(min(min(s8, s9), min(s10, s11)),
                      min(min(s12, s13), min(s14, s15))));
    idx = pair16_min(idx);
    idx = pair32_min(idx);

    if (lane < 16) {
      alpha_s[pw][jc] = m + xv;
      bp_s[(t - 1) * NN + jc] = (unsigned char)idx;
    }
    asm volatile("s_waitcnt lgkmcnt(0)\n\ts_barrier" ::: "memory");
  }

  const int pf = (slen - 1) & 1;
  float best = alpha_s[pf][lane];
  int last = lane;
#pragma unroll
  for (int mask = 1; mask < 64; mask <<= 1) {
    float ov = __shfl_xor(best, mask, 64);
    int oi = __shfl_xor(last, mask, 64);
    bool take = (ov > best) || (ov == best && oi < last);
    best = take ? ov : best;
    last = take ? oi : last;
  }
  const float lastf = (float)last;
  const int bTT = b * TT;

  for (int t = slen - 1 + tid; t < TT; t += 256) out[bTT + t] = lastf;
  if (tid == 0) out[BB * TT + b] = best;

  const int lo = 512 * w;
  const int hi = ((512 * (w + 1) - 1) < (slen - 2)) ? (512 * (w + 1) - 1)
                                                    : (slen - 2);
  if (w > 0) {
    int s = lane;
    for (int r = hi; r >= lo; --r) s = bp_s[r * NN + s];
    map_s[w][lane] = s;
  }
  __syncthreads();

  const int e3 = last;
  const int e2 = map_s[3][e3];
  const int e1 = map_s[2][e2];
  const int e0 = map_s[1][e1];
  const int entry = (w == 3) ? e3 : (w == 2) ? e2 : (w == 1) ? e1 : e0;

  if (lane == 0) {
    int s = entry;
    for (int r = hi; r >= lo; --r) {
      s = bp_s[r * NN + s];
      out[bTT + r] = (float)s;
    }
  }
}

extern "C" void kernel_launch(void* const* d_in, const int* in_sizes, int n_in,
                              void* d_out, int out_size, void* d_ws, size_t ws_size,
                              hipStream_t stream) {
  const float* x = (const float*)d_in[0];
  const int* seq_len = (const int*)d_in[1];
  const float* trans = (const float*)d_in[2];
  float* out = (float*)d_out;

  const size_t need = (size_t)BB * TT * NN * sizeof(float);  // 128 MiB history
  if (ws_size >= need) {
    crf_viterbi_fast<<<BB, 64, 0, stream>>>(x, seq_len, trans, out,
                                            (float*)d_ws);
  } else {
    crf_viterbi_fb<<<BB, 256, 0, stream>>>(x, seq_len, trans, out);
  }
}